// Round 1
// baseline (443.331 us; speedup 1.0000x reference)
//
#include <hip/hip_runtime.h>

#define BATCH      4096
#define FILTER_NUM 1024
#define REL_CNT    19
#define REL_DIM    1024

// Kernel 1: V[f,r] = sum_e U[f,e] * R[r,e]   (V = U @ R^T, [1024 x 19])
__global__ __launch_bounds__(256) void compute_V_kernel(
        const float* __restrict__ U,   // [FILTER_NUM, REL_DIM]
        const float* __restrict__ Rm,  // [REL_CNT, REL_DIM]
        float* __restrict__ V)         // [FILTER_NUM, REL_CNT]
{
    const int f   = blockIdx.x;
    const int tid = threadIdx.x;

    float acc[REL_CNT];
#pragma unroll
    for (int r = 0; r < REL_CNT; ++r) acc[r] = 0.0f;

    const float* __restrict__ Urow = U + (size_t)f * REL_DIM;
    for (int e = tid; e < REL_DIM; e += 256) {
        const float u = Urow[e];
#pragma unroll
        for (int r = 0; r < REL_CNT; ++r)
            acc[r] = fmaf(u, Rm[r * REL_DIM + e], acc[r]);
    }

    __shared__ float s[4][REL_CNT];
    const int lane = tid & 63;
    const int wave = tid >> 6;
#pragma unroll
    for (int r = 0; r < REL_CNT; ++r) {
        float v = acc[r];
#pragma unroll
        for (int off = 32; off > 0; off >>= 1)
            v += __shfl_down(v, off, 64);
        if (lane == 0) s[wave][r] = v;
    }
    __syncthreads();
    if (tid < REL_CNT)
        V[f * REL_CNT + tid] = s[0][tid] + s[1][tid] + s[2][tid] + s[3][tid];
}

// Kernel 2: scores[b,r] = sum_f conv[b,f,r] * V[f,r]
__global__ __launch_bounds__(256) void score_kernel(
        const float* __restrict__ conv,  // [BATCH, FILTER_NUM, REL_CNT]
        const float* __restrict__ V,     // [FILTER_NUM, REL_CNT]
        float* __restrict__ out)         // [BATCH, REL_CNT]
{
    const int b   = blockIdx.x;
    const int tid = threadIdx.x;

    const float* __restrict__ cb = conv + (size_t)b * FILTER_NUM * REL_CNT;

    float acc[REL_CNT];
#pragma unroll
    for (int r = 0; r < REL_CNT; ++r) acc[r] = 0.0f;

    for (int f = tid; f < FILTER_NUM; f += 256) {
        const float* __restrict__ c = cb + f * REL_CNT;
        const float* __restrict__ v = V  + f * REL_CNT;
#pragma unroll
        for (int r = 0; r < REL_CNT; ++r)
            acc[r] = fmaf(c[r], v[r], acc[r]);
    }

    __shared__ float s[4][REL_CNT];
    const int lane = tid & 63;
    const int wave = tid >> 6;
#pragma unroll
    for (int r = 0; r < REL_CNT; ++r) {
        float v = acc[r];
#pragma unroll
        for (int off = 32; off > 0; off >>= 1)
            v += __shfl_down(v, off, 64);
        if (lane == 0) s[wave][r] = v;
    }
    __syncthreads();
    if (tid < REL_CNT)
        out[b * REL_CNT + tid] = s[0][tid] + s[1][tid] + s[2][tid] + s[3][tid];
}

extern "C" void kernel_launch(void* const* d_in, const int* in_sizes, int n_in,
                              void* d_out, int out_size, void* d_ws, size_t ws_size,
                              hipStream_t stream) {
    // setup_inputs order: conv_output [B,F,R], R_output [R,E], U [F,E] — all fp32
    const float* conv = (const float*)d_in[0];
    const float* Rm   = (const float*)d_in[1];
    const float* U    = (const float*)d_in[2];
    float*       out  = (float*)d_out;
    float*       V    = (float*)d_ws;   // FILTER_NUM*REL_CNT floats = 77824*4 B

    compute_V_kernel<<<FILTER_NUM, 256, 0, stream>>>(U, Rm, V);
    score_kernel<<<BATCH, 256, 0, stream>>>(conv, V, out);
}

// Round 2
// 429.044 us; speedup vs baseline: 1.0333x; 1.0333x over previous
//
#include <hip/hip_runtime.h>

#define BATCH      4096
#define FILTER_NUM 1024
#define REL_CNT    19
#define REL_DIM    1024
#define SLAB       (FILTER_NUM * REL_CNT)   // 19456 floats per batch
#define ITERS      (SLAB / (256 * 4))       // 19 exactly

// Kernel 1: V[f,r] = sum_e U[f,e] * R[r,e]   (V = U @ R^T, [1024 x 19])
__global__ __launch_bounds__(256) void compute_V_kernel(
        const float* __restrict__ U,   // [FILTER_NUM, REL_DIM]
        const float* __restrict__ Rm,  // [REL_CNT, REL_DIM]
        float* __restrict__ V)         // [FILTER_NUM, REL_CNT]
{
    const int f   = blockIdx.x;
    const int tid = threadIdx.x;

    float acc[REL_CNT];
#pragma unroll
    for (int r = 0; r < REL_CNT; ++r) acc[r] = 0.0f;

    const float* __restrict__ Urow = U + (size_t)f * REL_DIM;
    for (int e = tid; e < REL_DIM; e += 256) {
        const float u = Urow[e];
#pragma unroll
        for (int r = 0; r < REL_CNT; ++r)
            acc[r] = fmaf(u, Rm[r * REL_DIM + e], acc[r]);
    }

    __shared__ float s[4][REL_CNT];
    const int lane = tid & 63;
    const int wave = tid >> 6;
#pragma unroll
    for (int r = 0; r < REL_CNT; ++r) {
        float v = acc[r];
#pragma unroll
        for (int off = 32; off > 0; off >>= 1)
            v += __shfl_down(v, off, 64);
        if (lane == 0) s[wave][r] = v;
    }
    __syncthreads();
    if (tid < REL_CNT)
        V[f * REL_CNT + tid] = s[0][tid] + s[1][tid] + s[2][tid] + s[3][tid];
}

// Kernel 2: scores[b, i%19] = sum over flat i of conv[b]_flat[i] * V_flat[i]
// All global loads are coalesced float4. Per-thread accumulators are indexed
// by compile-time phase j; actual relation r = (o + j) % 19 with o = (4*tid)%19,
// resolved once at the LDS reduction.
__global__ __launch_bounds__(256) void score_kernel(
        const float* __restrict__ conv,  // [BATCH, FILTER_NUM, REL_CNT]
        const float* __restrict__ V,     // [FILTER_NUM, REL_CNT] flat
        float* __restrict__ out)         // [BATCH, REL_CNT]
{
    const int b   = blockIdx.x;
    const int tid = threadIdx.x;

    const float4* __restrict__ c4 = (const float4*)(conv + (size_t)b * SLAB);
    const float4* __restrict__ v4 = (const float4*)V;

    const int o = (4 * tid) % REL_CNT;   // this thread's base phase

    float acc[REL_CNT];
#pragma unroll
    for (int j = 0; j < REL_CNT; ++j) acc[j] = 0.0f;

#pragma unroll
    for (int iter = 0; iter < ITERS; ++iter) {
        const int idx = iter * 256 + tid;
        const float4 c = c4[idx];
        const float4 v = v4[idx];
        // element k of this float4 has phase j = (17*iter + k) % 19 (static)
        acc[(17 * iter + 0) % REL_CNT] = fmaf(c.x, v.x, acc[(17 * iter + 0) % REL_CNT]);
        acc[(17 * iter + 1) % REL_CNT] = fmaf(c.y, v.y, acc[(17 * iter + 1) % REL_CNT]);
        acc[(17 * iter + 2) % REL_CNT] = fmaf(c.z, v.z, acc[(17 * iter + 2) % REL_CNT]);
        acc[(17 * iter + 3) % REL_CNT] = fmaf(c.w, v.w, acc[(17 * iter + 3) % REL_CNT]);
    }

    // Rotate into true-r columns in LDS: row = tid (stride 19 -> 2-way bank
    // aliasing, free on gfx950), col = (o + j) % 19.
    __shared__ float s[256 * REL_CNT];
#pragma unroll
    for (int j = 0; j < REL_CNT; ++j) {
        int r = o + j;
        if (r >= REL_CNT) r -= REL_CNT;
        s[tid * REL_CNT + r] = acc[j];
    }
    __syncthreads();

    // Stage A: 8 groups x 32 rows, one thread per (group, r): 152 active
    __shared__ float s2[8 * REL_CNT];
    if (tid < 8 * REL_CNT) {
        const int r = tid % REL_CNT;
        const int g = tid / REL_CNT;
        float sum = 0.0f;
#pragma unroll
        for (int i = 0; i < 32; ++i)
            sum += s[(g * 32 + i) * REL_CNT + r];
        s2[g * REL_CNT + r] = sum;
    }
    __syncthreads();

    // Stage B: final 8-way sum per r
    if (tid < REL_CNT) {
        float sum = 0.0f;
#pragma unroll
        for (int g = 0; g < 8; ++g)
            sum += s2[g * REL_CNT + tid];
        out[b * REL_CNT + tid] = sum;
    }
}

extern "C" void kernel_launch(void* const* d_in, const int* in_sizes, int n_in,
                              void* d_out, int out_size, void* d_ws, size_t ws_size,
                              hipStream_t stream) {
    // setup_inputs order: conv_output [B,F,R], R_output [R,E], U [F,E] — all fp32
    const float* conv = (const float*)d_in[0];
    const float* Rm   = (const float*)d_in[1];
    const float* U    = (const float*)d_in[2];
    float*       out  = (float*)d_out;
    float*       V    = (float*)d_ws;   // FILTER_NUM*REL_CNT floats

    compute_V_kernel<<<FILTER_NUM, 256, 0, stream>>>(U, Rm, V);
    score_kernel<<<BATCH, 256, 0, stream>>>(conv, V, out);
}

// Round 3
// 402.872 us; speedup vs baseline: 1.1004x; 1.0650x over previous
//
#include <hip/hip_runtime.h>

#define BATCH      4096
#define FILTER_NUM 1024
#define REL_CNT    19
#define REL_DIM    1024
#define SLAB       (FILTER_NUM * REL_CNT)   // 19456 floats per batch
#define ITERS      (SLAB / (256 * 4))       // 19 exactly

typedef float vf4 __attribute__((ext_vector_type(4)));

// Kernel 1: V[f,r] = sum_e U[f,e] * R[r,e]   (V = U @ R^T, [1024 x 19])
__global__ __launch_bounds__(256) void compute_V_kernel(
        const float* __restrict__ U,   // [FILTER_NUM, REL_DIM]
        const float* __restrict__ Rm,  // [REL_CNT, REL_DIM]
        float* __restrict__ V)         // [FILTER_NUM, REL_CNT]
{
    const int f   = blockIdx.x;
    const int tid = threadIdx.x;

    float acc[REL_CNT];
#pragma unroll
    for (int r = 0; r < REL_CNT; ++r) acc[r] = 0.0f;

    const float* __restrict__ Urow = U + (size_t)f * REL_DIM;
    for (int e = tid; e < REL_DIM; e += 256) {
        const float u = Urow[e];
#pragma unroll
        for (int r = 0; r < REL_CNT; ++r)
            acc[r] = fmaf(u, Rm[r * REL_DIM + e], acc[r]);
    }

    __shared__ float s[4][REL_CNT];
    const int lane = tid & 63;
    const int wave = tid >> 6;
#pragma unroll
    for (int r = 0; r < REL_CNT; ++r) {
        float v = acc[r];
#pragma unroll
        for (int off = 32; off > 0; off >>= 1)
            v += __shfl_down(v, off, 64);
        if (lane == 0) s[wave][r] = v;
    }
    __syncthreads();
    if (tid < REL_CNT)
        V[f * REL_CNT + tid] = s[0][tid] + s[1][tid] + s[2][tid] + s[3][tid];
}

// Kernel 2: two batch slabs per block; each v4 load serves both conv streams.
// conv loads are nontemporal (read-once stream). Static phase rotation:
// element k of float4 idx has r = (17*iter + o + k) % 19, o = (4*tid) % 19.
__global__ __launch_bounds__(256) void score_kernel(
        const float* __restrict__ conv,  // [BATCH, FILTER_NUM, REL_CNT]
        const float* __restrict__ V,     // [FILTER_NUM, REL_CNT] flat
        float* __restrict__ out)         // [BATCH, REL_CNT]
{
    const int b0  = blockIdx.x * 2;
    const int tid = threadIdx.x;

    const vf4* __restrict__ ca = (const vf4*)(conv + (size_t)b0 * SLAB);
    const vf4* __restrict__ cb = ca + (SLAB / 4);
    const vf4* __restrict__ v4 = (const vf4*)V;

    const int o = (4 * tid) % REL_CNT;

    float accA[REL_CNT], accB[REL_CNT];
#pragma unroll
    for (int j = 0; j < REL_CNT; ++j) { accA[j] = 0.0f; accB[j] = 0.0f; }

#pragma unroll
    for (int iter = 0; iter < ITERS; ++iter) {
        const int idx = iter * 256 + tid;
        const vf4 v  = v4[idx];
        const vf4 xa = __builtin_nontemporal_load(&ca[idx]);
        const vf4 xb = __builtin_nontemporal_load(&cb[idx]);
        const int j0 = (17 * iter + 0) % REL_CNT;
        const int j1 = (17 * iter + 1) % REL_CNT;
        const int j2 = (17 * iter + 2) % REL_CNT;
        const int j3 = (17 * iter + 3) % REL_CNT;
        accA[j0] = fmaf(xa.x, v.x, accA[j0]);
        accA[j1] = fmaf(xa.y, v.y, accA[j1]);
        accA[j2] = fmaf(xa.z, v.z, accA[j2]);
        accA[j3] = fmaf(xa.w, v.w, accA[j3]);
        accB[j0] = fmaf(xb.x, v.x, accB[j0]);
        accB[j1] = fmaf(xb.y, v.y, accB[j1]);
        accB[j2] = fmaf(xb.z, v.z, accB[j2]);
        accB[j3] = fmaf(xb.w, v.w, accB[j3]);
    }

    // LDS reduction, slab A then slab B (s reused; barriers order the phases).
    __shared__ float s[256 * REL_CNT];
    __shared__ float s2[8 * REL_CNT];

    // ---- slab A ----
#pragma unroll
    for (int j = 0; j < REL_CNT; ++j) {
        int r = o + j; if (r >= REL_CNT) r -= REL_CNT;
        s[tid * REL_CNT + r] = accA[j];
    }
    __syncthreads();
    if (tid < 8 * REL_CNT) {
        const int r = tid % REL_CNT;
        const int g = tid / REL_CNT;
        float sum = 0.0f;
#pragma unroll
        for (int i = 0; i < 32; ++i)
            sum += s[(g * 32 + i) * REL_CNT + r];
        s2[g * REL_CNT + r] = sum;
    }
    __syncthreads();
    if (tid < REL_CNT) {
        float sum = 0.0f;
#pragma unroll
        for (int g = 0; g < 8; ++g) sum += s2[g * REL_CNT + tid];
        out[b0 * REL_CNT + tid] = sum;
    }
    // ---- slab B ----  (s2 readers above finished before s2 rewrite: sync below)
#pragma unroll
    for (int j = 0; j < REL_CNT; ++j) {
        int r = o + j; if (r >= REL_CNT) r -= REL_CNT;
        s[tid * REL_CNT + r] = accB[j];   // safe: stage-A readers of s done at 2nd sync
    }
    __syncthreads();
    if (tid < 8 * REL_CNT) {
        const int r = tid % REL_CNT;
        const int g = tid / REL_CNT;
        float sum = 0.0f;
#pragma unroll
        for (int i = 0; i < 32; ++i)
            sum += s[(g * 32 + i) * REL_CNT + r];
        s2[g * REL_CNT + r] = sum;
    }
    __syncthreads();
    if (tid < REL_CNT) {
        float sum = 0.0f;
#pragma unroll
        for (int g = 0; g < 8; ++g) sum += s2[g * REL_CNT + tid];
        out[(b0 + 1) * REL_CNT + tid] = sum;
    }
}

extern "C" void kernel_launch(void* const* d_in, const int* in_sizes, int n_in,
                              void* d_out, int out_size, void* d_ws, size_t ws_size,
                              hipStream_t stream) {
    // setup_inputs order: conv_output [B,F,R], R_output [R,E], U [F,E] — all fp32
    const float* conv = (const float*)d_in[0];
    const float* Rm   = (const float*)d_in[1];
    const float* U    = (const float*)d_in[2];
    float*       out  = (float*)d_out;
    float*       V    = (float*)d_ws;   // FILTER_NUM*REL_CNT floats

    compute_V_kernel<<<FILTER_NUM, 256, 0, stream>>>(U, Rm, V);
    score_kernel<<<BATCH / 2, 256, 0, stream>>>(conv, V, out);
}